// Round 1
// baseline (965.309 us; speedup 1.0000x reference)
//
#include <hip/hip_runtime.h>
#include <hip/hip_bf16.h>

// ---------------------------------------------------------------------------
// RecursiveSortNet fp32 baseline:
//   xs = colsort(rowsort(colsort(x.reshape(B,64,64)))).reshape(B,4096)
//   h1 = relu(xs @ W1^T + b1)   [8192x512,  K=4096]
//   h2 = relu(h1 @ W2^T + b2)   [8192x256,  K=512 ]
//   out =      h2 @ W3^T + b3   [8192x4096, K=256 ]
// ---------------------------------------------------------------------------

#define B_DIM 8192
#define D_DIM 4096
#define H1_DIM 512
#define H2_DIM 256

// ---------------- in-register bitonic sort of 64 floats (ascending) --------
__device__ __forceinline__ void sort64(float v[64]) {
#pragma unroll
    for (int k = 2; k <= 64; k <<= 1) {
#pragma unroll
        for (int j = k >> 1; j > 0; j >>= 1) {
#pragma unroll
            for (int p = 0; p < 32; ++p) {
                const int i  = ((p & ~(j - 1)) << 1) | (p & (j - 1));
                const int ix = i | j;
                const bool up = ((i & k) == 0);   // compile-time after unroll
                float a = v[i], b = v[ix];
                float lo = fminf(a, b), hi = fmaxf(a, b);
                v[i]  = up ? lo : hi;
                v[ix] = up ? hi : lo;
            }
        }
    }
}

// One wave (64 lanes) per 64x64 matrix. Lane holds a COLUMN in registers so
// axis=1 sorts are pure in-register networks; axis=2 via LDS transpose.
__global__ __launch_bounds__(64)
void sort_kernel(const float* __restrict__ x, float* __restrict__ xs)
{
    __shared__ float lds[64 * 68];        // row-major, stride 68 (pad, 16B-aligned rows)
    const int b    = blockIdx.x;
    const int lane = threadIdx.x;
    const float* src = x  + (size_t)b * D_DIM;
    float*       dst = xs + (size_t)b * D_DIM;

    // ---- stage matrix into LDS row-major (coalesced float4 loads) ----
    float4 t[16];
#pragma unroll
    for (int q = 0; q < 16; ++q)
        t[q] = *(const float4*)(src + (q * 64 + lane) * 4);
#pragma unroll
    for (int q = 0; q < 16; ++q) {
        int f = q * 64 + lane;
        *(float4*)&lds[(f >> 4) * 68 + (f & 15) * 4] = t[q];
    }
    __syncthreads();

    // ---- lane <- column `lane` ----
    float v[64];
#pragma unroll
    for (int i = 0; i < 64; ++i) v[i] = lds[i * 68 + lane];

    sort64(v);                            // axis=1 (sort each column)

    // ---- transpose: lane <- row `lane` ----
    __syncthreads();
#pragma unroll
    for (int i = 0; i < 64; ++i) lds[i * 68 + lane] = v[i];
    __syncthreads();
#pragma unroll
    for (int q = 0; q < 16; ++q) {
        float4 r = *(const float4*)&lds[lane * 68 + q * 4];
        v[q * 4 + 0] = r.x; v[q * 4 + 1] = r.y;
        v[q * 4 + 2] = r.z; v[q * 4 + 3] = r.w;
    }

    sort64(v);                            // axis=2 (sort each row)

    // ---- transpose back: lane <- column `lane` ----
    __syncthreads();
#pragma unroll
    for (int q = 0; q < 16; ++q) {
        float4 r;
        r.x = v[q * 4 + 0]; r.y = v[q * 4 + 1];
        r.z = v[q * 4 + 2]; r.w = v[q * 4 + 3];
        *(float4*)&lds[lane * 68 + q * 4] = r;
    }
    __syncthreads();
#pragma unroll
    for (int i = 0; i < 64; ++i) v[i] = lds[i * 68 + lane];

    sort64(v);                            // axis=1 again

    // ---- write out row-major (coalesced float4 stores via LDS) ----
    __syncthreads();
#pragma unroll
    for (int i = 0; i < 64; ++i) lds[i * 68 + lane] = v[i];
    __syncthreads();
#pragma unroll
    for (int q = 0; q < 16; ++q) {
        int f = q * 64 + lane;
        float4 r = *(const float4*)&lds[(f >> 4) * 68 + (f & 15) * 4];
        *(float4*)(dst + f * 4) = r;
    }
}

// ---------------- fp32 tiled GEMM: C = act(A @ W^T + bias) ------------------
// A: MxK row-major, W: NxK row-major, C: MxN. BM=BN=64, BK=32, 256 threads,
// 4x4 accum per thread. LDS tiles stored k-major with XOR swizzle so that the
// k-contiguous global float4 loads scatter into LDS conflict-free while the
// compute side reads aligned conflict-free ds_read_b128.
__device__ __forceinline__ constexpr int swz(int kc) {
    return ((kc & 1) << 5) | (kc & 28);   // distinct mod 32 across the 8 lanes sharing a row
}

template<int BM, int BN, int BK, int TM, int TN, bool RELU>
__global__ __launch_bounds__(256)
void gemm_bias_act(const float* __restrict__ A, const float* __restrict__ W,
                   const float* __restrict__ bias, float* __restrict__ C,
                   int M, int N, int K)
{
    static_assert(BM == 64 && BN == 64 && BK == 32 && TM == 4 && TN == 4, "fixed config");
    __shared__ float sA[BK * BM];
    __shared__ float sB[BK * BN];
    const int tid = threadIdx.x;
    const int bn0 = blockIdx.x * BN;
    const int bm0 = blockIdx.y * BM;
    const int tx  = tid & 15;             // n-subtile
    const int ty  = tid >> 4;             // m-subtile

    float acc[TM][TN];
#pragma unroll
    for (int i = 0; i < TM; ++i)
#pragma unroll
        for (int j = 0; j < TN; ++j) acc[i][j] = 0.f;

    for (int k0 = 0; k0 < K; k0 += BK) {
        // A tile: 64 rows x 32 k, 512 float4 -> 2 per thread
#pragma unroll
        for (int s = 0; s < 2; ++s) {
            int f = tid + s * 256;
            int m = f >> 3, c4 = f & 7;
            float4 t = *(const float4*)(A + (size_t)(bm0 + m) * K + k0 + c4 * 4);
            const float* tp = (const float*)&t;
#pragma unroll
            for (int j = 0; j < 4; ++j) {
                int kc = c4 * 4 + j;
                sA[kc * BM + (m ^ swz(kc))] = tp[j];
            }
        }
        // W tile: 64 n x 32 k
#pragma unroll
        for (int s = 0; s < 2; ++s) {
            int f = tid + s * 256;
            int n = f >> 3, c4 = f & 7;
            float4 t = *(const float4*)(W + (size_t)(bn0 + n) * K + k0 + c4 * 4);
            const float* tp = (const float*)&t;
#pragma unroll
            for (int j = 0; j < 4; ++j) {
                int kc = c4 * 4 + j;
                sB[kc * BN + (n ^ swz(kc))] = tp[j];
            }
        }
        __syncthreads();

#pragma unroll
        for (int kk = 0; kk < BK; ++kk) {
            const int sw = swz(kk);
            float4 av = *(const float4*)&sA[kk * BM + ((ty * TM) ^ sw)];
            float4 bv = *(const float4*)&sB[kk * BN + ((tx * TN) ^ sw)];
            const float* ap = (const float*)&av;
            const float* bp = (const float*)&bv;
#pragma unroll
            for (int i = 0; i < TM; ++i)
#pragma unroll
                for (int j = 0; j < TN; ++j)
                    acc[i][j] = fmaf(ap[i], bp[j], acc[i][j]);
        }
        __syncthreads();
    }

    // epilogue: bias + optional relu, float4 stores
#pragma unroll
    for (int i = 0; i < TM; ++i) {
        int m = bm0 + ty * TM + i;
        int n = bn0 + tx * TN;
        float4 o;
        float* op = (float*)&o;
#pragma unroll
        for (int j = 0; j < TN; ++j) {
            float vv = acc[i][j] + bias[n + j];
            if (RELU) vv = fmaxf(vv, 0.f);
            op[j] = vv;
        }
        *(float4*)(C + (size_t)m * N + n) = o;
    }
}

// ---------------------------------------------------------------------------
extern "C" void kernel_launch(void* const* d_in, const int* in_sizes, int n_in,
                              void* d_out, int out_size, void* d_ws, size_t ws_size,
                              hipStream_t stream)
{
    const float* x  = (const float*)d_in[0];
    const float* W1 = (const float*)d_in[1];
    const float* b1 = (const float*)d_in[2];
    const float* W2 = (const float*)d_in[3];
    const float* b2 = (const float*)d_in[4];
    const float* W3 = (const float*)d_in[5];
    const float* b3 = (const float*)d_in[6];
    float* out = (float*)d_out;

    // xs reuses d_out (128 MB); GEMM3 overwrites it after GEMM1 consumed it.
    float* xs = out;
    float* h1 = (float*)d_ws;                            // 8192*512 = 16 MB
    float* h2 = h1 + (size_t)B_DIM * H1_DIM;             // 8192*256 =  8 MB

    sort_kernel<<<B_DIM, 64, 0, stream>>>(x, xs);

    gemm_bias_act<64, 64, 32, 4, 4, true>
        <<<dim3(H1_DIM / 64, B_DIM / 64), 256, 0, stream>>>(
            xs, W1, b1, h1, B_DIM, H1_DIM, D_DIM);

    gemm_bias_act<64, 64, 32, 4, 4, true>
        <<<dim3(H2_DIM / 64, B_DIM / 64), 256, 0, stream>>>(
            h1, W2, b2, h2, B_DIM, H2_DIM, H1_DIM);

    gemm_bias_act<64, 64, 32, 4, 4, false>
        <<<dim3(D_DIM / 64, B_DIM / 64), 256, 0, stream>>>(
            h2, W3, b3, out, B_DIM, D_DIM, H2_DIM);
}

// Round 2
// 391.727 us; speedup vs baseline: 2.4642x; 2.4642x over previous
//
#include <hip/hip_runtime.h>
#include <hip/hip_bf16.h>

// ---------------------------------------------------------------------------
// RecursiveSortNet — bf16 MFMA pipeline:
//   sort (fp32 in-register bitonic, emits xs as bf16)
//   h1 = relu(xs @ W1^T + b1)   bf16 MFMA, fp32 acc, bf16 out
//   h2 = relu(h1 @ W2^T + b2)   bf16 MFMA
//   out =      h2 @ W3^T + b3   bf16 MFMA, fp32 out
// ---------------------------------------------------------------------------

#define B_DIM 8192
#define D_DIM 4096
#define H1_DIM 512
#define H2_DIM 256

typedef __attribute__((ext_vector_type(8))) short bf16x8;
typedef __attribute__((ext_vector_type(4))) float f32x4;

__device__ __forceinline__ unsigned short f2bf(float f) {
    // round-to-nearest-even fp32 -> bf16 (inputs are finite; no NaN path)
    union { float f; unsigned u; } v{f};
    unsigned r = v.u + 0x7FFF + ((v.u >> 16) & 1);
    return (unsigned short)(r >> 16);
}

// ---------------- in-register bitonic sort of 64 floats (ascending) --------
__device__ __forceinline__ void sort64(float v[64]) {
#pragma unroll
    for (int k = 2; k <= 64; k <<= 1) {
#pragma unroll
        for (int j = k >> 1; j > 0; j >>= 1) {
#pragma unroll
            for (int p = 0; p < 32; ++p) {
                const int i  = ((p & ~(j - 1)) << 1) | (p & (j - 1));
                const int ix = i | j;
                const bool up = ((i & k) == 0);
                float a = v[i], b = v[ix];
                float lo = fminf(a, b), hi = fmaxf(a, b);
                v[i]  = up ? lo : hi;
                v[ix] = up ? hi : lo;
            }
        }
    }
}

// One wave per 64x64 matrix; lane = column. Emits bf16.
__global__ __launch_bounds__(64)
void sort_kernel(const float* __restrict__ x, unsigned short* __restrict__ xs)
{
    __shared__ float lds[64 * 68];
    const int b    = blockIdx.x;
    const int lane = threadIdx.x;
    const float* src = x + (size_t)b * D_DIM;
    unsigned short* dst = xs + (size_t)b * D_DIM;

    float4 t[16];
#pragma unroll
    for (int q = 0; q < 16; ++q)
        t[q] = *(const float4*)(src + (q * 64 + lane) * 4);
#pragma unroll
    for (int q = 0; q < 16; ++q) {
        int f = q * 64 + lane;
        *(float4*)&lds[(f >> 4) * 68 + (f & 15) * 4] = t[q];
    }
    __syncthreads();

    float v[64];
#pragma unroll
    for (int i = 0; i < 64; ++i) v[i] = lds[i * 68 + lane];
    sort64(v);                            // axis=1

    __syncthreads();
#pragma unroll
    for (int i = 0; i < 64; ++i) lds[i * 68 + lane] = v[i];
    __syncthreads();
#pragma unroll
    for (int q = 0; q < 16; ++q) {
        float4 r = *(const float4*)&lds[lane * 68 + q * 4];
        v[q * 4 + 0] = r.x; v[q * 4 + 1] = r.y;
        v[q * 4 + 2] = r.z; v[q * 4 + 3] = r.w;
    }
    sort64(v);                            // axis=2

    __syncthreads();
#pragma unroll
    for (int q = 0; q < 16; ++q) {
        float4 r;
        r.x = v[q * 4 + 0]; r.y = v[q * 4 + 1];
        r.z = v[q * 4 + 2]; r.w = v[q * 4 + 3];
        *(float4*)&lds[lane * 68 + q * 4] = r;
    }
    __syncthreads();
#pragma unroll
    for (int i = 0; i < 64; ++i) v[i] = lds[i * 68 + lane];
    sort64(v);                            // axis=1

    __syncthreads();
#pragma unroll
    for (int i = 0; i < 64; ++i) lds[i * 68 + lane] = v[i];
    __syncthreads();
#pragma unroll
    for (int q = 0; q < 16; ++q) {
        int f = q * 64 + lane;
        float4 r = *(const float4*)&lds[(f >> 4) * 68 + (f & 15) * 4];
        ushort4 o;
        o.x = f2bf(r.x); o.y = f2bf(r.y); o.z = f2bf(r.z); o.w = f2bf(r.w);
        *(ushort4*)(dst + f * 4) = o;
    }
}

// ---------------- fp32 -> bf16 weight conversion ---------------------------
__global__ __launch_bounds__(256)
void cvt_bf16(const float* __restrict__ src, unsigned short* __restrict__ dst, int n4)
{
    int i = blockIdx.x * blockDim.x + threadIdx.x;
    if (i < n4) {
        float4 v = ((const float4*)src)[i];
        ushort4 o;
        o.x = f2bf(v.x); o.y = f2bf(v.y); o.z = f2bf(v.z); o.w = f2bf(v.w);
        ((ushort4*)dst)[i] = o;
    }
}

// ---------------- bf16 MFMA GEMM: C = act(A @ W^T + bias) ------------------
// A: MxK bf16 row-major, W: NxK bf16 row-major. BK=64. 4 waves in 2x2.
// LDS tiles k-major, 64 bf16/row (8 segments of 16B), segment XOR-swizzled by
// (row&7): staging global_load_lds (wave-uniform base + lane*16) needs an
// unpadded contiguous layout; the swizzle is applied on the global SOURCE
// address (free), making compute-side ds_read_b128 conflict-free.
template<int BM, int BN, bool RELU, bool OUT_BF16>
__global__ __launch_bounds__(256, 2)
void gemm_mfma(const unsigned short* __restrict__ A,
               const unsigned short* __restrict__ Wt,
               const float* __restrict__ bias,
               void* __restrict__ Cout, int M, int N, int K)
{
    constexpr int BK  = 64;
    constexpr int WTM = BM / 2, WTN = BN / 2;
    constexpr int FM  = WTM / 16, FN = WTN / 16;
    __shared__ unsigned short sA[BM * BK];
    __shared__ unsigned short sB[BN * BK];

    const int tid  = threadIdx.x;
    const int wave = tid >> 6;
    const int lane = tid & 63;
    const int wm   = wave >> 1, wn = wave & 1;
    const int gm0  = blockIdx.y * BM;
    const int gn0  = blockIdx.x * BN;

    const int r_in = lane >> 3;   // row within 8-row staging chunk
    const int j_in = lane & 7;    // 16B segment slot within row

    f32x4 acc[FM][FN] = {};

    for (int k0 = 0; k0 < K; k0 += BK) {
        // ---- stage A tile: each instr = 8 rows x 64 bf16 = 1024B ----
#pragma unroll
        for (int c = 0; c < BM / 32; ++c) {
            int rb  = wave * (BM / 4) + c * 8;
            int r   = rb + r_in;
            int seg = j_in ^ (r & 7);
            const unsigned short* g = A + (size_t)(gm0 + r) * K + k0 + seg * 8;
            __builtin_amdgcn_global_load_lds(
                (const __attribute__((address_space(1))) void*)g,
                (__attribute__((address_space(3))) void*)&sA[rb * 64],
                16, 0, 0);
        }
        // ---- stage W tile ----
#pragma unroll
        for (int c = 0; c < BN / 32; ++c) {
            int rb  = wave * (BN / 4) + c * 8;
            int r   = rb + r_in;
            int seg = j_in ^ (r & 7);
            const unsigned short* g = Wt + (size_t)(gn0 + r) * K + k0 + seg * 8;
            __builtin_amdgcn_global_load_lds(
                (const __attribute__((address_space(1))) void*)g,
                (__attribute__((address_space(3))) void*)&sB[rb * 64],
                16, 0, 0);
        }
        __syncthreads();

#pragma unroll
        for (int ks = 0; ks < 2; ++ks) {
            bf16x8 afr[FM], bfr[FN];
#pragma unroll
            for (int i = 0; i < FM; ++i) {
                int m   = wm * WTM + i * 16 + (lane & 15);
                int seg = (ks * 4 + (lane >> 4)) ^ (m & 7);
                afr[i] = *(const bf16x8*)&sA[m * 64 + seg * 8];
            }
#pragma unroll
            for (int j = 0; j < FN; ++j) {
                int n   = wn * WTN + j * 16 + (lane & 15);
                int seg = (ks * 4 + (lane >> 4)) ^ (n & 7);
                bfr[j] = *(const bf16x8*)&sB[n * 64 + seg * 8];
            }
#pragma unroll
            for (int i = 0; i < FM; ++i)
#pragma unroll
                for (int j = 0; j < FN; ++j)
                    acc[i][j] = __builtin_amdgcn_mfma_f32_16x16x32_bf16(
                        afr[i], bfr[j], acc[i][j], 0, 0, 0);
        }
        __syncthreads();
    }

    // ---- epilogue: bias (+relu), store. D layout: col=lane&15, row=(lane>>4)*4+r
#pragma unroll
    for (int j = 0; j < FN; ++j) {
        int n = gn0 + wn * WTN + j * 16 + (lane & 15);
        float bv = bias[n];
#pragma unroll
        for (int i = 0; i < FM; ++i) {
#pragma unroll
            for (int r = 0; r < 4; ++r) {
                int m = gm0 + wm * WTM + i * 16 + (lane >> 4) * 4 + r;
                float v = acc[i][j][r] + bv;
                if (RELU) v = fmaxf(v, 0.f);
                if (OUT_BF16)
                    ((unsigned short*)Cout)[(size_t)m * N + n] = f2bf(v);
                else
                    ((float*)Cout)[(size_t)m * N + n] = v;
            }
        }
    }
}

// ---------------------------------------------------------------------------
extern "C" void kernel_launch(void* const* d_in, const int* in_sizes, int n_in,
                              void* d_out, int out_size, void* d_ws, size_t ws_size,
                              hipStream_t stream)
{
    const float* x  = (const float*)d_in[0];
    const float* W1 = (const float*)d_in[1];
    const float* b1 = (const float*)d_in[2];
    const float* W2 = (const float*)d_in[3];
    const float* b2 = (const float*)d_in[4];
    const float* W3 = (const float*)d_in[5];
    const float* b3 = (const float*)d_in[6];
    float* out = (float*)d_out;

    // xs (bf16, 64 MB) lives in d_out; GEMM3 overwrites d_out after GEMM1 read xs.
    unsigned short* xs = (unsigned short*)d_out;
    // workspace layout (18.25 MB total)
    char* ws = (char*)d_ws;
    unsigned short* h1b = (unsigned short*)(ws);                       //  8 MB
    unsigned short* h2b = (unsigned short*)(ws + (8u  << 20));        //  4 MB
    unsigned short* W1b = (unsigned short*)(ws + (12u << 20));        //  4 MB
    unsigned short* W2b = (unsigned short*)(ws + (16u << 20));        //  0.25 MB
    unsigned short* W3b = (unsigned short*)(ws + (17u << 20));        //  2 MB

    // weight conversions (must run every call — no caching allowed)
    cvt_bf16<<<(H1_DIM * D_DIM / 4 + 255) / 256, 256, 0, stream>>>(W1, W1b, H1_DIM * D_DIM / 4);
    cvt_bf16<<<(H2_DIM * H1_DIM / 4 + 255) / 256, 256, 0, stream>>>(W2, W2b, H2_DIM * H1_DIM / 4);
    cvt_bf16<<<(D_DIM * H2_DIM / 4 + 255) / 256, 256, 0, stream>>>(W3, W3b, D_DIM * H2_DIM / 4);

    sort_kernel<<<B_DIM, 64, 0, stream>>>(x, xs);

    // h1 = relu(xs @ W1^T + b1)  [8192 x 512, K=4096]  tile 128x64 -> 512 blocks
    gemm_mfma<128, 64, true, true>
        <<<dim3(H1_DIM / 64, B_DIM / 128), 256, 0, stream>>>(
            xs, W1b, b1, h1b, B_DIM, H1_DIM, D_DIM);

    // h2 = relu(h1 @ W2^T + b2)  [8192 x 256, K=512]   tile 64x64 -> 512 blocks
    gemm_mfma<64, 64, true, true>
        <<<dim3(H2_DIM / 64, B_DIM / 64), 256, 0, stream>>>(
            h1b, W2b, b2, h2b, B_DIM, H2_DIM, H1_DIM);

    // out = h2 @ W3^T + b3       [8192 x 4096, K=256]  tile 128x128 -> 2048 blocks
    gemm_mfma<128, 128, false, false>
        <<<dim3(D_DIM / 128, B_DIM / 128), 256, 0, stream>>>(
            h2b, W3b, b3, out, B_DIM, D_DIM, H2_DIM);
}

// Round 3
// 388.844 us; speedup vs baseline: 2.4825x; 1.0074x over previous
//
#include <hip/hip_runtime.h>
#include <hip/hip_bf16.h>

// ---------------------------------------------------------------------------
// RecursiveSortNet — bf16 MFMA pipeline, u16-key packed bitonic sort:
//   sort: round x to bf16 (monotone => commutes with sort), map to
//         order-preserving u16 keys, 3x bitonic-64 with v_pk_min/max_u16
//   h1 = relu(xs @ W1^T + b1)   bf16 MFMA, fp32 acc
//   h2 = relu(h1 @ W2^T + b2)
//   out =      h2 @ W3^T + b3   fp32 out
// ---------------------------------------------------------------------------

#define B_DIM 8192
#define D_DIM 4096
#define H1_DIM 512
#define H2_DIM 256

typedef unsigned short u16;
typedef __attribute__((ext_vector_type(2))) unsigned short u16x2;
typedef __attribute__((ext_vector_type(2))) short i16x2;
typedef __attribute__((ext_vector_type(8))) short bf16x8;
typedef __attribute__((ext_vector_type(4))) float f32x4;

__device__ __forceinline__ unsigned short f2bf(float f) {
    union { float f; unsigned u; } v{f};
    unsigned r = v.u + 0x7FFF + ((v.u >> 16) & 1);   // RNE, finite inputs
    return (unsigned short)(r >> 16);
}
// bf16 bits -> order-preserving u16 key
__device__ __forceinline__ u16 fkey(float f) {
    u16 bf = f2bf(f);
    u16 m  = (u16)(((short)bf) >> 15);               // 0xFFFF if negative
    return (u16)(bf ^ (m | 0x8000));
}
__device__ __forceinline__ u16x2 mk2(u16 a, u16 b) { u16x2 r; r.x = a; r.y = b; return r; }

#if defined(__has_builtin) && __has_builtin(__builtin_elementwise_min)
__device__ __forceinline__ u16x2 pkmin(u16x2 a, u16x2 b) { return __builtin_elementwise_min(a, b); }
__device__ __forceinline__ u16x2 pkmax(u16x2 a, u16x2 b) { return __builtin_elementwise_max(a, b); }
#else
__device__ __forceinline__ u16x2 pkmin(u16x2 a, u16x2 b) {
    return mk2(a.x < b.x ? a.x : b.x, a.y < b.y ? a.y : b.y);
}
__device__ __forceinline__ u16x2 pkmax(u16x2 a, u16x2 b) {
    return mk2(a.x > b.x ? a.x : b.x, a.y > b.y ? a.y : b.y);
}
#endif

// Bitonic sort of 64 u16 keys held as 32 packed regs, reg p = (elem p, elem p+32).
// For j<32 partners are in distinct regs (packed CE); j==32 is the in-reg stage.
// Direction is per-slot uniform except the k==32 phase (slot y descending).
__device__ __forceinline__ void sortnet(u16x2 v[32]) {
#pragma unroll
    for (int k = 2; k <= 64; k <<= 1) {
#pragma unroll
        for (int j = k >> 1; j >= 1; j >>= 1) {
            if (j == 32) {                     // k==64 only, ascending
#pragma unroll
                for (int p = 0; p < 32; ++p) {
                    u16x2 sw = mk2(v[p].y, v[p].x);
                    u16x2 mn = pkmin(v[p], sw), mx = pkmax(v[p], sw);
                    v[p] = mk2(mn.x, mx.y);
                }
            } else {
#pragma unroll
                for (int p = 0; p < 32; ++p) {
                    if (p & j) continue;
                    const int q = p | j;
                    const bool upx = ((p & k) == 0);
                    const bool upy = (((p + 32) & k) == 0);  // differs only at k==32
                    u16x2 mn = pkmin(v[p], v[q]), mx = pkmax(v[p], v[q]);
                    if (upx == upy) {
                        v[p] = upx ? mn : mx;
                        v[q] = upx ? mx : mn;
                    } else {                   // k==32: slot x asc, slot y desc
                        v[p] = mk2(mn.x, mx.y);
                        v[q] = mk2(mx.x, mn.y);
                    }
                }
            }
        }
    }
}

// 2 matrices per 128-thread block (1 per wave). LDS stride 66 u16 (all phases
// <=2-way bank aliasing == free). Row phases use a permuted row layout
// (dword p of row = elems (p, p+32)) matching the packed register mapping.
#define SRT 66
__global__ __launch_bounds__(128)
void sort_kernel(const float* __restrict__ x, u16* __restrict__ xs)
{
    __shared__ u16 smem[2 * 64 * SRT];
    const int wave = threadIdx.x >> 6;
    const int lane = threadIdx.x & 63;
    u16* s = smem + wave * 64 * SRT;
    const int b = blockIdx.x * 2 + wave;
    const float* src = x  + (size_t)b * D_DIM;
    u16*         dst = xs + (size_t)b * D_DIM;

    // ---- stage-in: coalesced float4 loads -> keys -> LDS standard layout ----
    float4 t[16];
#pragma unroll
    for (int qq = 0; qq < 16; ++qq)
        t[qq] = *(const float4*)(src + (qq * 64 + lane) * 4);
#pragma unroll
    for (int qq = 0; qq < 16; ++qq) {
        int f = qq * 64 + lane, r = f >> 4, c0 = (f & 15) * 4;
        *(u16x2*)&s[r * SRT + c0]     = mk2(fkey(t[qq].x), fkey(t[qq].y));
        *(u16x2*)&s[r * SRT + c0 + 2] = mk2(fkey(t[qq].z), fkey(t[qq].w));
    }
    __syncthreads();

    // ---- sort 1: columns (lane = column) ----
    u16x2 v[32];
#pragma unroll
    for (int p = 0; p < 32; ++p)
        v[p] = mk2(s[p * SRT + lane], s[(p + 32) * SRT + lane]);
    sortnet(v);

    // transpose-write, permuted row layout: row i pos (lane&31)*2+(lane>>5)
    __syncthreads();
    {
        const int pos = (lane & 31) * 2 + (lane >> 5);
#pragma unroll
        for (int p = 0; p < 32; ++p) {
            s[p * SRT + pos]        = v[p].x;
            s[(p + 32) * SRT + pos] = v[p].y;
        }
    }
    __syncthreads();

    // ---- sort 2: rows (lane = row); b32 reads land packed correctly ----
#pragma unroll
    for (int p = 0; p < 32; ++p)
        v[p] = *(const u16x2*)&s[lane * SRT + p * 2];
    sortnet(v);

    // transpose-write, standard layout
    __syncthreads();
#pragma unroll
    for (int p = 0; p < 32; ++p) {
        s[lane * SRT + p]      = v[p].x;
        s[lane * SRT + p + 32] = v[p].y;
    }
    __syncthreads();

    // ---- sort 3: columns again ----
#pragma unroll
    for (int p = 0; p < 32; ++p)
        v[p] = mk2(s[p * SRT + lane], s[(p + 32) * SRT + lane]);
    sortnet(v);

    // unmap keys -> bf16 bits (packed)
#pragma unroll
    for (int p = 0; p < 32; ++p) {
        i16x2 sh = ((i16x2)v[p]) >> 15;        // 0xFFFF where key bit15 set (orig >=0)
        u16x2 m  = (u16x2)sh;
        u16x2 c8; c8.x = 0x8000; c8.y = 0x8000;
        v[p] = v[p] ^ ((~m) | c8);
    }

    // transpose-write standard, then coalesced bf16 row stores
    __syncthreads();
#pragma unroll
    for (int p = 0; p < 32; ++p) {
        s[p * SRT + lane]        = v[p].x;
        s[(p + 32) * SRT + lane] = v[p].y;
    }
    __syncthreads();
#pragma unroll
    for (int qq = 0; qq < 16; ++qq) {
        int f = qq * 64 + lane, r = f >> 4, c0 = (f & 15) * 4;
        u16x2 a = *(const u16x2*)&s[r * SRT + c0];
        u16x2 c = *(const u16x2*)&s[r * SRT + c0 + 2];
        ushort4 o; o.x = a.x; o.y = a.y; o.z = c.x; o.w = c.y;
        *(ushort4*)(dst + f * 4) = o;
    }
}

// ---------------- fp32 -> bf16 weight conversion ---------------------------
__global__ __launch_bounds__(256)
void cvt_bf16(const float* __restrict__ src, unsigned short* __restrict__ dst, int n4)
{
    int i = blockIdx.x * blockDim.x + threadIdx.x;
    if (i < n4) {
        float4 v = ((const float4*)src)[i];
        ushort4 o;
        o.x = f2bf(v.x); o.y = f2bf(v.y); o.z = f2bf(v.z); o.w = f2bf(v.w);
        ((ushort4*)dst)[i] = o;
    }
}

// ---------------- bf16 MFMA GEMM: C = act(A @ W^T + bias) ------------------
template<int BM, int BN, bool RELU, bool OUT_BF16>
__global__ __launch_bounds__(256, 2)
void gemm_mfma(const unsigned short* __restrict__ A,
               const unsigned short* __restrict__ Wt,
               const float* __restrict__ bias,
               void* __restrict__ Cout, int M, int N, int K)
{
    constexpr int BK  = 64;
    constexpr int WTM = BM / 2, WTN = BN / 2;
    constexpr int FM  = WTM / 16, FN = WTN / 16;
    __shared__ unsigned short sA[BM * BK];
    __shared__ unsigned short sB[BN * BK];

    const int tid  = threadIdx.x;
    const int wave = tid >> 6;
    const int lane = tid & 63;
    const int wm   = wave >> 1, wn = wave & 1;
    const int gm0  = blockIdx.y * BM;
    const int gn0  = blockIdx.x * BN;

    const int r_in = lane >> 3;
    const int j_in = lane & 7;

    f32x4 acc[FM][FN] = {};

    for (int k0 = 0; k0 < K; k0 += BK) {
#pragma unroll
        for (int c = 0; c < BM / 32; ++c) {
            int rb  = wave * (BM / 4) + c * 8;
            int r   = rb + r_in;
            int seg = j_in ^ (r & 7);
            const unsigned short* g = A + (size_t)(gm0 + r) * K + k0 + seg * 8;
            __builtin_amdgcn_global_load_lds(
                (const __attribute__((address_space(1))) void*)g,
                (__attribute__((address_space(3))) void*)&sA[rb * 64],
                16, 0, 0);
        }
#pragma unroll
        for (int c = 0; c < BN / 32; ++c) {
            int rb  = wave * (BN / 4) + c * 8;
            int r   = rb + r_in;
            int seg = j_in ^ (r & 7);
            const unsigned short* g = Wt + (size_t)(gn0 + r) * K + k0 + seg * 8;
            __builtin_amdgcn_global_load_lds(
                (const __attribute__((address_space(1))) void*)g,
                (__attribute__((address_space(3))) void*)&sB[rb * 64],
                16, 0, 0);
        }
        __syncthreads();

#pragma unroll
        for (int ks = 0; ks < 2; ++ks) {
            bf16x8 afr[FM], bfr[FN];
#pragma unroll
            for (int i = 0; i < FM; ++i) {
                int m   = wm * WTM + i * 16 + (lane & 15);
                int seg = (ks * 4 + (lane >> 4)) ^ (m & 7);
                afr[i] = *(const bf16x8*)&sA[m * 64 + seg * 8];
            }
#pragma unroll
            for (int j = 0; j < FN; ++j) {
                int n   = wn * WTN + j * 16 + (lane & 15);
                int seg = (ks * 4 + (lane >> 4)) ^ (n & 7);
                bfr[j] = *(const bf16x8*)&sB[n * 64 + seg * 8];
            }
#pragma unroll
            for (int i = 0; i < FM; ++i)
#pragma unroll
                for (int j = 0; j < FN; ++j)
                    acc[i][j] = __builtin_amdgcn_mfma_f32_16x16x32_bf16(
                        afr[i], bfr[j], acc[i][j], 0, 0, 0);
        }
        __syncthreads();
    }

#pragma unroll
    for (int j = 0; j < FN; ++j) {
        int n = gn0 + wn * WTN + j * 16 + (lane & 15);
        float bv = bias[n];
#pragma unroll
        for (int i = 0; i < FM; ++i) {
#pragma unroll
            for (int r = 0; r < 4; ++r) {
                int m = gm0 + wm * WTM + i * 16 + (lane >> 4) * 4 + r;
                float v = acc[i][j][r] + bv;
                if (RELU) v = fmaxf(v, 0.f);
                if (OUT_BF16)
                    ((unsigned short*)Cout)[(size_t)m * N + n] = f2bf(v);
                else
                    ((float*)Cout)[(size_t)m * N + n] = v;
            }
        }
    }
}

// ---------------------------------------------------------------------------
extern "C" void kernel_launch(void* const* d_in, const int* in_sizes, int n_in,
                              void* d_out, int out_size, void* d_ws, size_t ws_size,
                              hipStream_t stream)
{
    const float* x  = (const float*)d_in[0];
    const float* W1 = (const float*)d_in[1];
    const float* b1 = (const float*)d_in[2];
    const float* W2 = (const float*)d_in[3];
    const float* b2 = (const float*)d_in[4];
    const float* W3 = (const float*)d_in[5];
    const float* b3 = (const float*)d_in[6];
    float* out = (float*)d_out;

    // xs (bf16, 64 MB) lives in d_out; GEMM3 overwrites d_out after GEMM1 read xs.
    u16* xs = (u16*)d_out;
    char* ws = (char*)d_ws;
    unsigned short* h1b = (unsigned short*)(ws);                      //  8 MB
    unsigned short* h2b = (unsigned short*)(ws + (8u  << 20));        //  4 MB
    unsigned short* W1b = (unsigned short*)(ws + (12u << 20));        //  4 MB
    unsigned short* W2b = (unsigned short*)(ws + (16u << 20));        //  0.25 MB
    unsigned short* W3b = (unsigned short*)(ws + (17u << 20));        //  2 MB

    sort_kernel<<<B_DIM / 2, 128, 0, stream>>>(x, xs);

    cvt_bf16<<<(H1_DIM * D_DIM / 4 + 255) / 256, 256, 0, stream>>>(W1, W1b, H1_DIM * D_DIM / 4);
    cvt_bf16<<<(H2_DIM * H1_DIM / 4 + 255) / 256, 256, 0, stream>>>(W2, W2b, H2_DIM * H1_DIM / 4);
    cvt_bf16<<<(D_DIM * H2_DIM / 4 + 255) / 256, 256, 0, stream>>>(W3, W3b, D_DIM * H2_DIM / 4);

    // h1 = relu(xs @ W1^T + b1)  [8192 x 512, K=4096]  tile 128x64
    gemm_mfma<128, 64, true, true>
        <<<dim3(H1_DIM / 64, B_DIM / 128), 256, 0, stream>>>(
            xs, W1b, b1, h1b, B_DIM, H1_DIM, D_DIM);

    // h2 = relu(h1 @ W2^T + b2)  [8192 x 256, K=512]   tile 128x64
    gemm_mfma<128, 64, true, true>
        <<<dim3(H2_DIM / 64, B_DIM / 128), 256, 0, stream>>>(
            h1b, W2b, b2, h2b, B_DIM, H2_DIM, H1_DIM);

    // out = h2 @ W3^T + b3       [8192 x 4096, K=256]  tile 128x128
    gemm_mfma<128, 128, false, false>
        <<<dim3(D_DIM / 128, B_DIM / 128), 256, 0, stream>>>(
            h2b, W3b, b3, out, B_DIM, D_DIM, H2_DIM);
}